// Round 7
// baseline (891.442 us; speedup 1.0000x reference)
//
#include <hip/hip_runtime.h>

// Problem constants (match the reference)
constexpr int B_     = 16384;
constexpr int NNUM   = 32;
constexpr int NCAT   = 8;
constexpr int NCOLS  = 40;   // NNUM + NCAT
constexpr int DD     = 256;
constexpr int CC     = 16;

constexpr int BDIM     = 256;
constexpr int NBLOCKS  = 2048;
constexpr int NWAVES   = NBLOCKS * (BDIM / 64);  // 8192
constexpr int NW_CAT   = 2048;                   // 256 waves per categorical column
constexpr int NW_NUM   = NWAVES - NW_CAT;        // 6144
constexpr int NUM_CELLS = B_ * NNUM;             // 524288 (even; pairs never split)

constexpr int OUT_NUM_SZ  = B_ * NNUM;           // 524288
constexpr int OUT_CAT_SZ  = B_ * NCAT * CC;      // 2097152

__global__ __launch_bounds__(BDIM, 4)
void tabdec_kernel(const float* __restrict__ X,
                   const float* __restrict__ w_num,  const float* __restrict__ b_num,
                   const float* __restrict__ W_cat,  const float* __restrict__ b_cat,
                   const float* __restrict__ w_miss, const float* __restrict__ b_miss,
                   float* __restrict__ out_num, float* __restrict__ out_cat,
                   float* __restrict__ out_miss)
{
    const int tid  = blockIdx.x * BDIM + threadIdx.x;
    const int wid  = tid >> 6;
    const int lane = threadIdx.x & 63;
    const float4* __restrict__ Xv = reinterpret_cast<const float4*>(X);

    if (wid < NW_NUM) {
        // ---------------- numeric cells: num_pred + miss, 2 cells/iter ----------------
        const float4 wn = reinterpret_cast<const float4*>(w_num)[lane];
        const float4 wm = reinterpret_cast<const float4*>(w_miss)[lane];
        const float bn = b_num[0];
        const float bm = b_miss[0];
        for (int i = 2 * wid; i < NUM_CELLS; i += 2 * NW_NUM) {
            // i even -> j0 in {0,2,...,30}; cells i and i+1 share table row b
            const int b = i >> 5;
            const int j = i & 31;
            const int row0 = b * NCOLS + j;
            const float4 x0 = Xv[row0 * (DD / 4) + lane];
            const float4 x1 = Xv[(row0 + 1) * (DD / 4) + lane];
            float pn0 = x0.x * wn.x + x0.y * wn.y + x0.z * wn.z + x0.w * wn.w;
            float pm0 = x0.x * wm.x + x0.y * wm.y + x0.z * wm.z + x0.w * wm.w;
            float pn1 = x1.x * wn.x + x1.y * wn.y + x1.z * wn.z + x1.w * wn.w;
            float pm1 = x1.x * wm.x + x1.y * wm.y + x1.z * wm.z + x1.w * wm.w;
            #pragma unroll
            for (int m = 1; m < 64; m <<= 1) {
                pn0 += __shfl_xor(pn0, m, 64);
                pn1 += __shfl_xor(pn1, m, 64);
                pm0 += __shfl_xor(pm0, m, 64);
                pm1 += __shfl_xor(pm1, m, 64);
            }
            if (lane == 0) {
                out_num[i]     = pn0 + bn;
                out_num[i + 1] = pn1 + bn;
                out_miss[row0]     = pm0 + bm;
                out_miss[row0 + 1] = pm1 + bm;
            }
        }
    } else {
        // ---------------- categorical cells: 16 logits + miss ----------------
        const int wc = wid - NW_NUM;     // 0..2047
        const int j  = wc >> 8;          // column 0..7 (fixed per wave -> W in regs)
        const int b0 = wc & 255;
        const float* Wj = W_cat + j * DD * CC;

        // W fragment: rows d = lane*4+k (k<4), all 16 classes. 64 VGPRs.
        float4 w0[4], w1[4], w2[4], w3[4];
        #pragma unroll
        for (int k = 0; k < 4; ++k) {
            const float4* wr = reinterpret_cast<const float4*>(Wj + (lane * 4 + k) * CC);
            w0[k] = wr[0]; w1[k] = wr[1]; w2[k] = wr[2]; w3[k] = wr[3];
        }
        const float4 wm = reinterpret_cast<const float4*>(w_miss)[lane];
        const float bm = b_miss[0];
        // after split-butterfly, lane l ends holding class c = bitrev4(l&15)
        const int cbr = ((lane & 1) << 3) | ((lane & 2) << 1) | ((lane & 4) >> 1) | ((lane & 8) >> 3);
        const float bias = b_cat[j * CC + cbr];
        const bool h1 = lane & 1, h2 = lane & 2, h3 = lane & 4, h4 = lane & 8;

        for (int b = b0; b < B_; b += 256) {
            const int row = b * NCOLS + NNUM + j;
            const float4 x = Xv[row * (DD / 4) + lane];
            const float xe0 = x.x, xe1 = x.y, xe2 = x.z, xe3 = x.w;

            float p[16];
            #pragma unroll
            for (int c = 0; c < 16; ++c) p[c] = 0.0f;
            #define ACC(k, xk) \
                p[0]  += xk * w0[k].x; p[1]  += xk * w0[k].y; p[2]  += xk * w0[k].z; p[3]  += xk * w0[k].w; \
                p[4]  += xk * w1[k].x; p[5]  += xk * w1[k].y; p[6]  += xk * w1[k].z; p[7]  += xk * w1[k].w; \
                p[8]  += xk * w2[k].x; p[9]  += xk * w2[k].y; p[10] += xk * w2[k].z; p[11] += xk * w2[k].w; \
                p[12] += xk * w3[k].x; p[13] += xk * w3[k].y; p[14] += xk * w3[k].z; p[15] += xk * w3[k].w;
            ACC(0, xe0) ACC(1, xe1) ACC(2, xe2) ACC(3, xe3)
            #undef ACC

            float pm = x.x * wm.x + x.y * wm.y + x.z * wm.z + x.w * wm.w;

            // split butterfly: halve value count while reducing over lane bits 0..3
            float q[8];
            #pragma unroll
            for (int i = 0; i < 8; ++i) {
                const float send = h1 ? p[i] : p[i + 8];
                const float keep = h1 ? p[i + 8] : p[i];
                q[i] = keep + __shfl_xor(send, 1, 64);
            }
            float r[4];
            #pragma unroll
            for (int i = 0; i < 4; ++i) {
                const float send = h2 ? q[i] : q[i + 4];
                const float keep = h2 ? q[i + 4] : q[i];
                r[i] = keep + __shfl_xor(send, 2, 64);
            }
            float s[2];
            #pragma unroll
            for (int i = 0; i < 2; ++i) {
                const float send = h3 ? r[i] : r[i + 2];
                const float keep = h3 ? r[i + 2] : r[i];
                s[i] = keep + __shfl_xor(send, 4, 64);
            }
            {
                const float send = h4 ? s[0] : s[1];
                const float keep = h4 ? s[1] : s[0];
                s[0] = keep + __shfl_xor(send, 8, 64);
            }
            float t = s[0];
            t += __shfl_xor(t, 16, 64);
            t += __shfl_xor(t, 32, 64);

            #pragma unroll
            for (int m = 1; m < 64; m <<= 1) pm += __shfl_xor(pm, m, 64);

            if (lane < 16) out_cat[b * (NCAT * CC) + j * CC + cbr] = t + bias;
            if (lane == 0) out_miss[b * NCOLS + NNUM + j] = pm + bm;
        }
    }
}

extern "C" void kernel_launch(void* const* d_in, const int* in_sizes, int n_in,
                              void* d_out, int out_size, void* d_ws, size_t ws_size,
                              hipStream_t stream) {
    const float* X      = (const float*)d_in[0];
    const float* w_num  = (const float*)d_in[1];
    const float* b_num  = (const float*)d_in[2];
    const float* W_cat  = (const float*)d_in[3];
    const float* b_cat  = (const float*)d_in[4];
    const float* w_miss = (const float*)d_in[5];
    const float* b_miss = (const float*)d_in[6];

    float* out_num  = (float*)d_out;
    float* out_cat  = out_num + OUT_NUM_SZ;
    float* out_miss = out_cat + OUT_CAT_SZ;

    tabdec_kernel<<<NBLOCKS, BDIM, 0, stream>>>(X, w_num, b_num, W_cat, b_cat,
                                                w_miss, b_miss,
                                                out_num, out_cat, out_miss);
}

// Round 8
// 882.995 us; speedup vs baseline: 1.0096x; 1.0096x over previous
//
#include <hip/hip_runtime.h>

// Problem constants (match the reference)
constexpr int B_     = 16384;
constexpr int NNUM   = 32;
constexpr int NCAT   = 8;
constexpr int NCOLS  = 40;   // NNUM + NCAT
constexpr int DD     = 256;
constexpr int CC     = 16;

constexpr int OUT_NUM_SZ  = B_ * NNUM;           // 524288
constexpr int OUT_CAT_SZ  = B_ * NCAT * CC;      // 2097152
constexpr int NUM_CELLS   = B_ * NNUM;           // 524288

// ---------------- numeric kernel: 32 waves/CU, 4 cells/iter ----------------
constexpr int NB_NUM   = 2048;                   // blocks
constexpr int NWAVE_N  = NB_NUM * 4;             // 8192 waves
// iterations per wave = NUM_CELLS / (4 * NWAVE_N) = 16 exactly

__global__ __launch_bounds__(256, 8)             // <=64 VGPR -> 32 waves/CU
void tabdec_num(const float* __restrict__ X,
                const float* __restrict__ w_num,  const float* __restrict__ b_num,
                const float* __restrict__ w_miss, const float* __restrict__ b_miss,
                float* __restrict__ out_num, float* __restrict__ out_miss)
{
    const int wid  = (blockIdx.x * 256 + threadIdx.x) >> 6;
    const int lane = threadIdx.x & 63;
    const float4* __restrict__ Xv = reinterpret_cast<const float4*>(X);

    const float4 wn = reinterpret_cast<const float4*>(w_num)[lane];
    const float4 wm = reinterpret_cast<const float4*>(w_miss)[lane];
    const float bn = b_num[0];
    const float bm = b_miss[0];

    const bool bit0 = lane & 1, bit1 = lane & 2, bit2 = lane & 4;
    // after split-butterfly: lane l<8 holds cell (l>>1); even lane = num, odd = miss
    const int cellsel = (lane >> 1) & 3;

    for (int i = 4 * wid; i < NUM_CELLS; i += 4 * NWAVE_N) {
        // i % 4 == 0 -> j0 in {0,4,...,28}; 4 cells share table row-block b
        const int b    = i >> 5;
        const int j    = i & 31;
        const int row0 = b * NCOLS + j;

        const float4 x0 = Xv[(row0 + 0) * (DD / 4) + lane];
        const float4 x1 = Xv[(row0 + 1) * (DD / 4) + lane];
        const float4 x2 = Xv[(row0 + 2) * (DD / 4) + lane];
        const float4 x3 = Xv[(row0 + 3) * (DD / 4) + lane];

        float pn0 = x0.x*wn.x + x0.y*wn.y + x0.z*wn.z + x0.w*wn.w;
        float pm0 = x0.x*wm.x + x0.y*wm.y + x0.z*wm.z + x0.w*wm.w;
        float pn1 = x1.x*wn.x + x1.y*wn.y + x1.z*wn.z + x1.w*wn.w;
        float pm1 = x1.x*wm.x + x1.y*wm.y + x1.z*wm.z + x1.w*wm.w;
        float pn2 = x2.x*wn.x + x2.y*wn.y + x2.z*wn.z + x2.w*wn.w;
        float pm2 = x2.x*wm.x + x2.y*wm.y + x2.z*wm.z + x2.w*wm.w;
        float pn3 = x3.x*wn.x + x3.y*wn.y + x3.z*wn.z + x3.w*wn.w;
        float pm3 = x3.x*wm.x + x3.y*wm.y + x3.z*wm.z + x3.w*wm.w;

        // split-butterfly: 8 values -> 1 per lane while reducing lane bits 0..2,
        // then 3 plain xor levels complete the 64-lane sum. 10 shuffles total.
        // level 1 (mask 1): fold num/miss into lane bit0
        float q0, q1, q2, q3;
        { float k0 = bit0 ? pm0 : pn0, s0 = bit0 ? pn0 : pm0; q0 = k0 + __shfl_xor(s0, 1, 64); }
        { float k1 = bit0 ? pm1 : pn1, s1 = bit0 ? pn1 : pm1; q1 = k1 + __shfl_xor(s1, 1, 64); }
        { float k2 = bit0 ? pm2 : pn2, s2 = bit0 ? pn2 : pm2; q2 = k2 + __shfl_xor(s2, 1, 64); }
        { float k3 = bit0 ? pm3 : pn3, s3 = bit0 ? pn3 : pm3; q3 = k3 + __shfl_xor(s3, 1, 64); }
        // level 2 (mask 2): fold cell{0,1} / cell{2,3} into lane bit1
        float r0, r1;
        { float k = bit1 ? q0 : q1, kk = bit1 ? q1 : q0; r0 = kk + __shfl_xor(k, 2, 64); }
        { float k = bit1 ? q2 : q3, kk = bit1 ? q3 : q2; r1 = kk + __shfl_xor(k, 2, 64); }
        // level 3 (mask 4): fold cell-pair into lane bit2
        float s;
        { float k = bit2 ? r0 : r1, kk = bit2 ? r1 : r0; s = kk + __shfl_xor(k, 4, 64); }
        // remaining lane bits
        s += __shfl_xor(s, 8, 64);
        s += __shfl_xor(s, 16, 64);
        s += __shfl_xor(s, 32, 64);

        if (lane < 8) {
            if (!bit0) out_num[i + cellsel]     = s + bn;
            else       out_miss[row0 + cellsel] = s + bm;
        }
    }
}

// ---------------- categorical kernel: W in regs, 512 waves/column ----------------
constexpr int NB_CAT  = 1024;                    // blocks
constexpr int NWAVE_C = NB_CAT * 4;              // 4096 waves; j = wid>>9

__global__ __launch_bounds__(256, 4)             // <=128 VGPR (W frag = 64)
void tabdec_cat(const float* __restrict__ X,
                const float* __restrict__ W_cat,  const float* __restrict__ b_cat,
                const float* __restrict__ w_miss, const float* __restrict__ b_miss,
                float* __restrict__ out_cat, float* __restrict__ out_miss)
{
    const int wid  = (blockIdx.x * 256 + threadIdx.x) >> 6;
    const int lane = threadIdx.x & 63;
    const float4* __restrict__ Xv = reinterpret_cast<const float4*>(X);

    const int j  = wid >> 9;          // column 0..7 (fixed per wave -> W in regs)
    const int b0 = wid & 511;
    const float* Wj = W_cat + j * DD * CC;

    // W fragment: rows d = lane*4+k (k<4), all 16 classes. 64 VGPRs.
    float4 w0[4], w1[4], w2[4], w3[4];
    #pragma unroll
    for (int k = 0; k < 4; ++k) {
        const float4* wr = reinterpret_cast<const float4*>(Wj + (lane * 4 + k) * CC);
        w0[k] = wr[0]; w1[k] = wr[1]; w2[k] = wr[2]; w3[k] = wr[3];
    }
    const float4 wm = reinterpret_cast<const float4*>(w_miss)[lane];
    const float bm = b_miss[0];
    // after split-butterfly, lane l ends holding class c = bitrev4(l&15)
    const int cbr = ((lane & 1) << 3) | ((lane & 2) << 1) | ((lane & 4) >> 1) | ((lane & 8) >> 3);
    const float bias = b_cat[j * CC + cbr];
    const bool h1 = lane & 1, h2 = lane & 2, h3 = lane & 4, h4 = lane & 8;

    for (int b = b0; b < B_; b += 512) {
        const int row = b * NCOLS + NNUM + j;
        const float4 x = Xv[row * (DD / 4) + lane];
        const float xe0 = x.x, xe1 = x.y, xe2 = x.z, xe3 = x.w;

        float p[16];
        #pragma unroll
        for (int c = 0; c < 16; ++c) p[c] = 0.0f;
        #define ACC(k, xk) \
            p[0]  += xk * w0[k].x; p[1]  += xk * w0[k].y; p[2]  += xk * w0[k].z; p[3]  += xk * w0[k].w; \
            p[4]  += xk * w1[k].x; p[5]  += xk * w1[k].y; p[6]  += xk * w1[k].z; p[7]  += xk * w1[k].w; \
            p[8]  += xk * w2[k].x; p[9]  += xk * w2[k].y; p[10] += xk * w2[k].z; p[11] += xk * w2[k].w; \
            p[12] += xk * w3[k].x; p[13] += xk * w3[k].y; p[14] += xk * w3[k].z; p[15] += xk * w3[k].w;
        ACC(0, xe0) ACC(1, xe1) ACC(2, xe2) ACC(3, xe3)
        #undef ACC

        float pm = x.x * wm.x + x.y * wm.y + x.z * wm.z + x.w * wm.w;

        // split butterfly over lane bits 0..3
        float q[8];
        #pragma unroll
        for (int i = 0; i < 8; ++i) {
            const float send = h1 ? p[i] : p[i + 8];
            const float keep = h1 ? p[i + 8] : p[i];
            q[i] = keep + __shfl_xor(send, 1, 64);
        }
        float r[4];
        #pragma unroll
        for (int i = 0; i < 4; ++i) {
            const float send = h2 ? q[i] : q[i + 4];
            const float keep = h2 ? q[i + 4] : q[i];
            r[i] = keep + __shfl_xor(send, 2, 64);
        }
        float ss[2];
        #pragma unroll
        for (int i = 0; i < 2; ++i) {
            const float send = h3 ? r[i] : r[i + 2];
            const float keep = h3 ? r[i + 2] : r[i];
            ss[i] = keep + __shfl_xor(send, 4, 64);
        }
        {
            const float send = h4 ? ss[0] : ss[1];
            const float keep = h4 ? ss[1] : ss[0];
            ss[0] = keep + __shfl_xor(send, 8, 64);
        }
        float t = ss[0];
        t += __shfl_xor(t, 16, 64);
        t += __shfl_xor(t, 32, 64);

        #pragma unroll
        for (int m = 1; m < 64; m <<= 1) pm += __shfl_xor(pm, m, 64);

        if (lane < 16) out_cat[b * (NCAT * CC) + j * CC + cbr] = t + bias;
        if (lane == 0) out_miss[b * NCOLS + NNUM + j] = pm + bm;
    }
}

extern "C" void kernel_launch(void* const* d_in, const int* in_sizes, int n_in,
                              void* d_out, int out_size, void* d_ws, size_t ws_size,
                              hipStream_t stream) {
    const float* X      = (const float*)d_in[0];
    const float* w_num  = (const float*)d_in[1];
    const float* b_num  = (const float*)d_in[2];
    const float* W_cat  = (const float*)d_in[3];
    const float* b_cat  = (const float*)d_in[4];
    const float* w_miss = (const float*)d_in[5];
    const float* b_miss = (const float*)d_in[6];

    float* out_num  = (float*)d_out;
    float* out_cat  = out_num + OUT_NUM_SZ;
    float* out_miss = out_cat + OUT_CAT_SZ;

    tabdec_num<<<NB_NUM, 256, 0, stream>>>(X, w_num, b_num, w_miss, b_miss,
                                           out_num, out_miss);
    tabdec_cat<<<NB_CAT, 256, 0, stream>>>(X, W_cat, b_cat, w_miss, b_miss,
                                           out_cat, out_miss);
}